// Round 16
// baseline (210.781 us; speedup 1.0000x reference)
//
#include <hip/hip_runtime.h>
#include <stdint.h>

// ---------------------------------------------------------------------------
// SelfAttentionRope fused pipeline (round 16)
//   B=4 T=2048 D=1024 H=16 DH=64   M = B*T = 8192
//   R14 retro: 64-q/wave died on LIVENESS (4 S-accs + 4 O-accs live at once
//   = 296 regs -> 1 wave/SIMD), not on the idea. Fix: sequential q-sets --
//   QK-A, softpack-A (frees sA), QK-B, softpack-B, PV-both. O-accs are
//   MFMA-only (no-max softmax) -> AGPR-resident for free. Peak ~230 regs
//   -> 2 waves/SIMD. kf/vf read once per 64 q: per-q LDS BW halved.
//   Prep + tri-buffer gemms from R15 unchanged.
// ---------------------------------------------------------------------------

typedef float  f32x4  __attribute__((ext_vector_type(4)));
typedef float  f32x16 __attribute__((ext_vector_type(16)));
typedef short  s16x8  __attribute__((ext_vector_type(8)));
typedef unsigned int u32x4 __attribute__((ext_vector_type(4)));
typedef unsigned short u16;
typedef unsigned int   u32;

#define LOG2E 1.4426950408889634f

__device__ __forceinline__ u16 f2bf(float f) {
  u32 u = __float_as_uint(f);
  u32 r = (u + 0x7fffu + ((u >> 16) & 1u)) >> 16;   // RNE
  return (u16)r;
}

__device__ __forceinline__ u32 cvtpk_bf16(float lo, float hi) {
  u32 w;
  asm("v_cvt_pk_bf16_f32 %0, %1, %2" : "=v"(w) : "v"(lo), "v"(hi));
  return w;
}

// single-instruction exp2, IR-visible (hazard-safe first reader of MFMA acc)
__device__ __forceinline__ float fexp2(float x) {
  return __builtin_amdgcn_exp2f(x);
}

// async global -> LDS, 16 B per lane (dest = wave-uniform base + lane*16)
__device__ __forceinline__ void gload_lds16(const u16* g, u16* l) {
  __builtin_amdgcn_global_load_lds(
      (const __attribute__((address_space(1))) uint32_t*)g,
      (__attribute__((address_space(3))) uint32_t*)l, 16, 0, 0);
}

// ---- fused prep: cvt | transpose Wqkv | transpose Wproj | rope table -----
__device__ __forceinline__ void transpose_body(
    const float* __restrict__ W, u16* __restrict__ Wt,
    int rows, int cols, int bx, int by, int t, float* tile /*[32][33]*/)
{
  int k0 = by * 32, n0 = bx * 32;
  int c = t & 31, r0 = t >> 5;
  #pragma unroll
  for (int i = 0; i < 4; i++) {
    int r = r0 + i * 8;
    tile[r * 33 + c] = W[(size_t)(k0 + r) * cols + n0 + c];
  }
  __syncthreads();
  int kk = t & 31, nn0 = t >> 5;
  #pragma unroll
  for (int i = 0; i < 4; i++) {
    int nn = nn0 + i * 8;
    Wt[(size_t)(n0 + nn) * rows + k0 + kk] = f2bf(tile[kk * 33 + nn]);
  }
}

__global__ void prep_kernel(const float* __restrict__ x, u16* __restrict__ xb,
                            const float* __restrict__ Wqkv, u16* __restrict__ Wqkvt,
                            const float* __restrict__ Wproj, u16* __restrict__ Wprojt,
                            float* __restrict__ rsin, float* __restrict__ rcos) {
  __shared__ float tile[32 * 33];
  int bid = blockIdx.x, t = threadIdx.x;
  if (bid < 4096) {                       // x f32 -> bf16, 8 elems/thread
    int i = bid * 256 + t;
    const float4* p = reinterpret_cast<const float4*>(x) + (size_t)i * 2;
    float4 a = p[0], b = p[1];
    u32 w0 = (u32)f2bf(a.x) | ((u32)f2bf(a.y) << 16);
    u32 w1 = (u32)f2bf(a.z) | ((u32)f2bf(a.w) << 16);
    u32 w2 = (u32)f2bf(b.x) | ((u32)f2bf(b.y) << 16);
    u32 w3 = (u32)f2bf(b.z) | ((u32)f2bf(b.w) << 16);
    reinterpret_cast<uint4*>(xb)[i] = make_uint4(w0, w1, w2, w3);
  } else if (bid < 4096 + 3072) {         // Wqkv [1024][3072] -> Wt
    int bb = bid - 4096;
    transpose_body(Wqkv, Wqkvt, 1024, 3072, bb % 96, bb / 96, t, tile);
  } else if (bid < 4096 + 3072 + 1024) {  // Wproj [1024][1024] -> Wt
    int bb = bid - 7168;
    transpose_body(Wproj, Wprojt, 1024, 1024, bb % 32, bb / 32, t, tile);
  } else {                                // rope table [2048][32]
    int idx = (bid - 8192) * 256 + t;
    int tt = idx >> 5, i = idx & 31;
    float invf = 1.0f / powf(10000.0f, (float)i * (1.0f / 32.0f));
    float ang = (float)tt * invf;
    rsin[idx] = sinf(ang);
    rcos[idx] = cosf(ang);
  }
}

// ---- shared epilogue helper (MODE 0 scatter) -----------------------------
__device__ __forceinline__ void qkv_scatter_frag(
    int wavecol, int rbase, int l15, f32x4* accm /* [4] fc frags */,
    const float* bias, const float* rsin, const float* rcos,
    u16* Qg, u16* Kg, u16* Vtg)
{
  int sec = wavecol >> 10;
  int h = (wavecol & 1023) >> 6;
  if (sec < 2) {
    u16* G = (sec == 0) ? Qg : Kg;
    float qs = (sec == 0) ? 0.125f * LOG2E : 1.0f;
    #pragma unroll
    for (int fc = 0; fc < 2; fc++) {
      int dh = fc * 16 + l15;
      float b1 = bias[wavecol + fc * 16 + l15];
      float b2 = bias[wavecol + fc * 16 + l15 + 32];
      #pragma unroll
      for (int j = 0; j < 4; j++) {
        int grow = rbase + j;
        int bidx = grow >> 11, tt = grow & 2047;
        float sn = rsin[tt * 32 + dh], cs = rcos[tt * 32 + dh];
        float v1 = accm[fc][j] + b1;
        float v2 = accm[fc + 2][j] + b2;
        float lo = (v1 * cs - v2 * sn) * qs;
        float hi = (v1 * sn + v2 * cs) * qs;
        size_t base = ((size_t)(bidx * 16 + h) * 2048 + tt) * 64;
        G[base + dh]      = f2bf(lo);
        G[base + dh + 32] = f2bf(hi);
      }
    }
  } else {
    #pragma unroll
    for (int fc = 0; fc < 4; fc++) {
      int dh = fc * 16 + l15;
      float bb = bias[wavecol + fc * 16 + l15];
      #pragma unroll
      for (int j = 0; j < 4; j++) {
        int grow = rbase + j;
        int bidx = grow >> 11, tt = grow & 2047;
        Vtg[((size_t)(bidx * 16 + h) * 64 + dh) * 2048 + tt] = f2bf(accm[fc][j] + bb);
      }
    }
  }
}

// ---- 3a) GEMM 128^2 (proven m97-structure; fallback) ---------------------
template<int MODE>
__global__ __launch_bounds__(256) void gemm_kernel(
    const u16* __restrict__ A, const u16* __restrict__ Bt,
    const float* __restrict__ bias,
    const float* __restrict__ rsin, const float* __restrict__ rcos,
    u16* __restrict__ Qg, u16* __restrict__ Kg, u16* __restrict__ Vtg,
    float* __restrict__ Cout, int K)
{
  __shared__ alignas(16) u16 As[128][64];
  __shared__ alignas(16) u16 Bs[128][64];
  int tid = threadIdx.x;
  int lane = tid & 63, wid = tid >> 6;
  int wr = wid >> 1, wc = wid & 1;
  int l15 = lane & 15, lg = lane >> 4;
  int row0 = blockIdx.x * 128, col0 = blockIdx.y * 128;

  f32x4 acc[4][4] = {};

  int sr = lane >> 3, sc = lane & 7;
  int scol = (sc ^ sr) * 8;                       // pre-swizzled source col
  const u16* asrc = A  + (size_t)(row0 + wid * 32 + sr) * K + scol;
  const u16* bsrc = Bt + (size_t)(col0 + wid * 32 + sr) * K + scol;
  u16* aLds = &As[0][0] + wid * 2048;
  u16* bLds = &Bs[0][0] + wid * 2048;

  for (int k0 = 0; k0 < K; k0 += 64) {
    #pragma unroll
    for (int i = 0; i < 4; i++) {
      gload_lds16(asrc + (size_t)(i * 8) * K + k0, aLds + i * 512);
      gload_lds16(bsrc + (size_t)(i * 8) * K + k0, bLds + i * 512);
    }
    __syncthreads();
    #pragma unroll
    for (int kk = 0; kk < 2; kk++) {
      s16x8 af[4], bf[4];
      #pragma unroll
      for (int m = 0; m < 4; m++) {
        int row = wr * 64 + m * 16 + l15;
        int slot = (kk * 4 + lg) ^ (l15 & 7);
        af[m] = *reinterpret_cast<const s16x8*>(&As[row][slot * 8]);
      }
      #pragma unroll
      for (int n = 0; n < 4; n++) {
        int row = wc * 64 + n * 16 + l15;
        int slot = (kk * 4 + lg) ^ (l15 & 7);
        bf[n] = *reinterpret_cast<const s16x8*>(&Bs[row][slot * 8]);
      }
      #pragma unroll
      for (int m = 0; m < 4; m++)
        #pragma unroll
        for (int n = 0; n < 4; n++)
          acc[m][n] = __builtin_amdgcn_mfma_f32_16x16x32_bf16(af[m], bf[n], acc[m][n], 0, 0, 0);
    }
    __syncthreads();
  }

  if (MODE == 0) {
    int wavecol = col0 + wc * 64;
    #pragma unroll
    for (int m = 0; m < 4; m++) {
      int rbase = row0 + wr * 64 + m * 16 + lg * 4;
      qkv_scatter_frag(wavecol, rbase, l15, acc[m], bias, rsin, rcos, Qg, Kg, Vtg);
    }
  } else {
    #pragma unroll
    for (int m = 0; m < 4; m++) {
      int grow = row0 + wr * 64 + m * 16 + lg * 4;
      #pragma unroll
      for (int fc = 0; fc < 4; fc++) {
        int col = col0 + wc * 64 + fc * 16 + l15;
        float bb = bias[col];
        #pragma unroll
        for (int j = 0; j < 4; j++)
          Cout[(size_t)(grow + j) * 1024 + col] = acc[m][fc][j] + bb;
      }
    }
  }
}

// ---- 3b) GEMM 128x256, 8 waves, 4-phase, TRI-buffer counted vmcnt --------
template<int MODE>
__global__ __launch_bounds__(512, 2) void gemm8_kernel(
    const u16* __restrict__ A, const u16* __restrict__ Bt,
    const float* __restrict__ bias,
    const float* __restrict__ rsin, const float* __restrict__ rcos,
    u16* __restrict__ Qg, u16* __restrict__ Kg, u16* __restrict__ Vtg,
    float* __restrict__ Cout, int K)
{
  extern __shared__ u16 lds[];
  int tid = threadIdx.x;
  int lane = tid & 63, wid = tid >> 6;       // 8 waves
  int wr = wid >> 2, wc = wid & 3;           // 2 x 4
  int l15 = lane & 15, lg = lane >> 4;
  int row0 = blockIdx.x * 128, col0 = blockIdx.y * 256;

  f32x4 acc[4][4] = {};

  int sr = lane >> 3, sc = lane & 7;
  int scol = (sc ^ sr) * 8;                  // pre-swizzled source col
  const u16* asrc = A  + (size_t)(row0 + wid * 16 + sr) * K + scol;
  const u16* bsrc = Bt + (size_t)(col0 + wid * 32 + sr) * K + scol;

  #pragma unroll
  for (int i = 0; i < 2; i++)
    gload_lds16(asrc + (size_t)(i * 8) * K, lds + wid * 1024 + i * 512);
  #pragma unroll
  for (int i = 0; i < 4; i++)
    gload_lds16(bsrc + (size_t)(i * 8) * K, lds + 8192 + wid * 2048 + i * 512);
  #pragma unroll
  for (int i = 0; i < 2; i++)
    gload_lds16(asrc + (size_t)(i * 8) * K + 64, lds + 24576 + wid * 1024 + i * 512);
  #pragma unroll
  for (int i = 0; i < 4; i++)
    gload_lds16(bsrc + (size_t)(i * 8) * K + 64, lds + 24576 + 8192 + wid * 2048 + i * 512);
  asm volatile("s_waitcnt vmcnt(6)");   // oldest 6 (= tile 0) complete
  __builtin_amdgcn_s_barrier();

  const int nt = K >> 6;
  int cur = 0;
  for (int g = 0; g < nt; ++g) {
    const u16* aB = lds + cur * 24576;
    const u16* bB = aB + 8192;
    int nxt = cur + 2; if (nxt >= 3) nxt -= 3;
    u16* aD = lds + nxt * 24576 + wid * 1024;
    u16* bD = lds + nxt * 24576 + 8192 + wid * 2048;
    size_t kn2 = (size_t)(g + 2) << 6;
    bool pre = (g + 2 < nt);

    s16x8 bf[4];
    #pragma unroll
    for (int p = 0; p < 4; p++) {
      const int kk = p >> 1, mh = p & 1;
      const int slotx = (kk * 4 + lg);
      s16x8 af[2];
      #pragma unroll
      for (int mi = 0; mi < 2; mi++) {
        int row = wr * 64 + (mh * 2 + mi) * 16 + l15;
        int slot = slotx ^ (l15 & 7);
        af[mi] = *reinterpret_cast<const s16x8*>(aB + row * 64 + slot * 8);
      }
      if (mh == 0) {
        #pragma unroll
        for (int n = 0; n < 4; n++) {
          int row = wc * 64 + n * 16 + l15;
          int slot = slotx ^ (l15 & 7);
          bf[n] = *reinterpret_cast<const s16x8*>(bB + row * 64 + slot * 8);
        }
      }
      if (p == 0 && pre) {
        #pragma unroll
        for (int i = 0; i < 2; i++)
          gload_lds16(asrc + (size_t)(i * 8) * K + kn2, aD + i * 512);
        #pragma unroll
        for (int i = 0; i < 4; i++)
          gload_lds16(bsrc + (size_t)(i * 8) * K + kn2, bD + i * 512);
      }
      __builtin_amdgcn_s_barrier();
      __builtin_amdgcn_s_setprio(1);
      #pragma unroll
      for (int mi = 0; mi < 2; mi++)
        #pragma unroll
        for (int n = 0; n < 4; n++)
          acc[mh * 2 + mi][n] =
              __builtin_amdgcn_mfma_f32_16x16x32_bf16(af[mi], bf[n], acc[mh * 2 + mi][n], 0, 0, 0);
      __builtin_amdgcn_s_setprio(0);
      __builtin_amdgcn_s_barrier();
    }
    if (pre) {
      asm volatile("s_waitcnt vmcnt(6)");
      __builtin_amdgcn_s_barrier();
    } else if (g + 1 < nt) {
      asm volatile("s_waitcnt vmcnt(0)");
      __builtin_amdgcn_s_barrier();
    }
    cur += 1; if (cur >= 3) cur -= 3;
  }

  if (MODE == 0) {
    int wavecol = col0 + wc * 64;
    #pragma unroll
    for (int m = 0; m < 4; m++) {
      int rbase = row0 + wr * 64 + m * 16 + lg * 4;
      qkv_scatter_frag(wavecol, rbase, l15, acc[m], bias, rsin, rcos, Qg, Kg, Vtg);
    }
  } else {
    #pragma unroll
    for (int m = 0; m < 4; m++) {
      int grow = row0 + wr * 64 + m * 16 + lg * 4;
      #pragma unroll
      for (int fc = 0; fc < 4; fc++) {
        int col = col0 + wc * 64 + fc * 16 + l15;
        float bb = bias[col];
        #pragma unroll
        for (int j = 0; j < 4; j++)
          Cout[(size_t)(grow + j) * 1024 + col] = acc[m][fc][j] + bb;
      }
    }
  }
}

// ---- 4) flash attention: 4 waves x 64 q, SEQUENTIAL q-set phasing --------
// grid bx = qt*64 + bh (qt 0..7), 512 blocks. kf[8]/vf read once per tile,
// feed both q-sets. Per tile: QK-A -> softpack-A (sA freed) -> QK-B ->
// softpack-B (sB,kf freed) -> PV both. O-accs MFMA-only => AGPR-resident.
__global__ __launch_bounds__(256) void attn_kernel(
    const u16* __restrict__ Qg, const u16* __restrict__ Kg, const u16* __restrict__ Vtg,
    u16* __restrict__ Og)
{
  __shared__ alignas(16) u16 Ks[2][4096];   // [key][dh] swizzled (16B chunks)
  __shared__ alignas(16) u16 Vs[2][4096];   // [d][key]  swizzled
  int tid = threadIdx.x;
  int lane = tid & 63, wid = tid >> 6;      // wid 0..3
  int l31 = lane & 31, hi = lane >> 5;
  int bh = blockIdx.x & 63, qt = blockIdx.x >> 6;   // qt 0..7
  int q = qt * 256 + wid * 64 + l31;        // set A; set B = q+32
  size_t bh2048 = (size_t)bh * 2048;

  // Q B-frags for both sets (Q pre-scaled by 0.125*log2e)
  s16x8 aqA[4], aqB[4];
  #pragma unroll
  for (int kc = 0; kc < 4; kc++) {
    aqA[kc] = *reinterpret_cast<const s16x8*>(Qg + (bh2048 + q) * 64 + kc * 16 + hi * 8);
    aqB[kc] = *reinterpret_cast<const s16x8*>(Qg + (bh2048 + q + 32) * 64 + kc * 16 + hi * 8);
  }

  f32x16 oA0 = {}, oA1 = {}, oB0 = {}, oB1 = {};
  float lA = 0.f, lB = 0.f;

  int sr = lane >> 3, sc = lane & 7;
  int scol = (sc ^ sr) * 8;
  const u16* kg0 = Kg  + (bh2048 + wid * 16 + sr) * 64 + scol;
  const u16* kg1 = kg0 + 8 * 64;
  const u16* vg0 = Vtg + ((size_t)bh * 64 + wid * 16 + sr) * 2048 + scol;
  const u16* vg1 = vg0 + 8 * 2048;
  int sdst = wid * 1024;

  int offs[2][4];
  #pragma unroll
  for (int c = 0; c < 2; c++)
    #pragma unroll
    for (int j = 0; j < 4; j++)
      offs[c][j] = (c * 32 + l31) * 64 + (((j * 2 + hi) ^ (l31 & 7)) * 8);

#define STAGE(TT, BUF) do { \
    gload_lds16(kg0 + (size_t)(TT) * 4096, &Ks[BUF][sdst]); \
    gload_lds16(kg1 + (size_t)(TT) * 4096, &Ks[BUF][sdst + 512]); \
    gload_lds16(vg0 + (size_t)(TT) * 64,   &Vs[BUF][sdst]); \
    gload_lds16(vg1 + (size_t)(TT) * 64,   &Vs[BUF][sdst + 512]); \
  } while (0)

// softmax+pack for one q-set: s0,s1 in place -> pf[4]; lrun accumulated
#define SOFTPACK(s0, s1, lrun, pf) do { \
    _Pragma("unroll") \
    for (int i = 0; i < 16; i++) { \
      s0[i] = fexp2(s0[i]); \
      s1[i] = fexp2(s1[i]); \
    } \
    float r0 = 0.f, r1 = 0.f, r2 = 0.f, r3 = 0.f; \
    _Pragma("unroll") \
    for (int i = 0; i < 4; i++) { \
      r0 += s0[i] + s0[i + 8]; \
      r1 += s0[i + 4] + s0[i + 12]; \
      r2 += s1[i] + s1[i + 8]; \
      r3 += s1[i + 4] + s1[i + 12]; \
    } \
    float rs = (r0 + r1) + (r2 + r3); \
    rs += __shfl_xor(rs, 32); \
    lrun += rs; \
    _Pragma("unroll") \
    for (int ks = 0; ks < 2; ks++) { \
      int rr = ks * 8; \
      u32 a0 = cvtpk_bf16(s0[rr + 0], s0[rr + 1]); \
      u32 b0 = cvtpk_bf16(s0[rr + 4], s0[rr + 5]); \
      u32 a1 = cvtpk_bf16(s0[rr + 2], s0[rr + 3]); \
      u32 b1 = cvtpk_bf16(s0[rr + 6], s0[rr + 7]); \
      asm volatile("v_permlane32_swap_b32 %0, %1" : "+v"(a0), "+v"(b0)); \
      asm volatile("v_permlane32_swap_b32 %0, %1" : "+v"(a1), "+v"(b1)); \
      u32x4 w = {a0, a1, b0, b1}; \
      pf[ks] = __builtin_bit_cast(s16x8, w); \
    } \
    _Pragma("unroll") \
    for (int ks = 0; ks < 2; ks++) { \
      int rr = ks * 8; \
      u32 a0 = cvtpk_bf16(s1[rr + 0], s1[rr + 1]); \
      u32 b0 = cvtpk_bf16(s1[rr + 4], s1[rr + 5]); \
      u32 a1 = cvtpk_bf16(s1[rr + 2], s1[rr + 3]); \
      u32 b1 = cvtpk_bf16(s1[rr + 6], s1[rr + 7]); \
      asm volatile("v_permlane32_swap_b32 %0, %1" : "+v"(a0), "+v"(b0)); \
      asm volatile("v_permlane32_swap_b32 %0, %1" : "+v"(a1), "+v"(b1)); \
      u32x4 w = {a0, a1, b0, b1}; \
      pf[ks + 2] = __builtin_bit_cast(s16x8, w); \
    } \
  } while (0)

#define COMPUTE(B) do { \
    const u16* kb = &Ks[B][0]; \
    const u16* vb = &Vs[B][0]; \
    s16x8 kf[8]; \
    _Pragma("unroll") \
    for (int j = 0; j < 4; j++) { \
      kf[j]     = *reinterpret_cast<const s16x8*>(kb + offs[0][j]); \
      kf[4 + j] = *reinterpret_cast<const s16x8*>(kb + offs[1][j]); \
    } \
    s16x8 pfA[4], pfB[4]; \
    { \
      f32x16 sA0 = {}, sA1 = {}; \
      __builtin_amdgcn_s_setprio(1); \
      _Pragma("unroll") \
      for (int j = 0; j < 4; j++) { \
        sA0 = __builtin_amdgcn_mfma_f32_32x32x16_bf16(kf[j],     aqA[j], sA0, 0, 0, 0); \
        sA1 = __builtin_amdgcn_mfma_f32_32x32x16_bf16(kf[4 + j], aqA[j], sA1, 0, 0, 0); \
      } \
      __builtin_amdgcn_s_setprio(0); \
      SOFTPACK(sA0, sA1, lA, pfA); \
    } \
    { \
      f32x16 sB0 = {}, sB1 = {}; \
      __builtin_amdgcn_s_setprio(1); \
      _Pragma("unroll") \
      for (int j = 0; j < 4; j++) { \
        sB0 = __builtin_amdgcn_mfma_f32_32x32x16_bf16(kf[j],     aqB[j], sB0, 0, 0, 0); \
        sB1 = __builtin_amdgcn_mfma_f32_32x32x16_bf16(kf[4 + j], aqB[j], sB1, 0, 0, 0); \
      } \
      __builtin_amdgcn_s_setprio(0); \
      SOFTPACK(sB0, sB1, lB, pfB); \
    } \
    __builtin_amdgcn_s_setprio(1); \
    _Pragma("unroll") \
    for (int ks = 0; ks < 4; ks++) { \
      s16x8 vf0 = *reinterpret_cast<const s16x8*>(vb + offs[0][ks]); \
      oA0 = __builtin_amdgcn_mfma_f32_32x32x16_bf16(vf0, pfA[ks], oA0, 0, 0, 0); \
      oB0 = __builtin_amdgcn_mfma_f32_32x32x16_bf16(vf0, pfB[ks], oB0, 0, 0, 0); \
    } \
    _Pragma("unroll") \
    for (int ks = 0; ks < 4; ks++) { \
      s16x8 vf1 = *reinterpret_cast<const s16x8*>(vb + offs[1][ks]); \
      oA1 = __builtin_amdgcn_mfma_f32_32x32x16_bf16(vf1, pfA[ks], oA1, 0, 0, 0); \
      oB1 = __builtin_amdgcn_mfma_f32_32x32x16_bf16(vf1, pfB[ks], oB1, 0, 0, 0); \
    } \
    __builtin_amdgcn_s_setprio(0); \
  } while (0)

  STAGE(0, 0);
  __syncthreads();

  for (int it = 0; it < 16; it++) {
    STAGE(2 * it + 1, 1);
    COMPUTE(0);
    __syncthreads();          // drains stage->b1; b0 reads complete
    if (it < 15) STAGE(2 * it + 2, 0);
    COMPUTE(1);
    __syncthreads();          // drains stage->b0; b1 reads complete
  }
#undef STAGE
#undef COMPUTE
#undef SOFTPACK

  // epilogue: normalize (lane-local) and store both q-sets
  int b = bh >> 4, h = bh & 15;
  {
    float inv = 1.0f / lA;
    size_t rowbase = ((size_t)b * 2048 + q) * 1024 + h * 64;
    #pragma unroll
    for (int c2 = 0; c2 < 2; c2++) {
      #pragma unroll
      for (int g = 0; g < 4; g++) {
        float e0 = (c2 ? oA1[g * 4 + 0] : oA0[g * 4 + 0]) * inv;
        float e1 = (c2 ? oA1[g * 4 + 1] : oA0[g * 4 + 1]) * inv;
        float e2 = (c2 ? oA1[g * 4 + 2] : oA0[g * 4 + 2]) * inv;
        float e3 = (c2 ? oA1[g * 4 + 3] : oA0[g * 4 + 3]) * inv;
        u32 w0 = cvtpk_bf16(e0, e1);
        u32 w1 = cvtpk_bf16(e2, e3);
        int d = c2 * 32 + g * 8 + hi * 4;
        uint2 val; val.x = w0; val.y = w1;
        *reinterpret_cast<uint2*>(Og + rowbase + d) = val;
      }
    }
  }
  {
    float inv = 1.0f / lB;
    size_t rowbase = ((size_t)b * 2048 + q + 32) * 1024 + h * 64;
    #pragma unroll
    for (int c2 = 0; c2 < 2; c2++) {
      #pragma unroll
      for (int g = 0; g < 4; g++) {
        float e0 = (c2 ? oB1[g * 4 + 0] : oB0[g * 4 + 0]) * inv;
        float e1 = (c2 ? oB1[g * 4 + 1] : oB0[g * 4 + 1]) * inv;
        float e2 = (c2 ? oB1[g * 4 + 2] : oB0[g * 4 + 2]) * inv;
        float e3 = (c2 ? oB1[g * 4 + 3] : oB0[g * 4 + 3]) * inv;
        u32 w0 = cvtpk_bf16(e0, e1);
        u32 w1 = cvtpk_bf16(e2, e3);
        int d = c2 * 32 + g * 8 + hi * 4;
        uint2 val; val.x = w0; val.y = w1;
        *reinterpret_cast<uint2*>(Og + rowbase + d) = val;
      }
    }
  }
}

// ---------------------------------------------------------------------------
extern "C" void kernel_launch(void* const* d_in, const int* in_sizes, int n_in,
                              void* d_out, int out_size, void* d_ws, size_t ws_size,
                              hipStream_t stream) {
  const float* x     = (const float*)d_in[0];
  const float* Wqkv  = (const float*)d_in[1];
  const float* bqkv  = (const float*)d_in[2];
  const float* Wproj = (const float*)d_in[3];
  const float* bproj = (const float*)d_in[4];
  float* out = (float*)d_out;

  char* ws = (char*)d_ws;
  size_t off = 0;
  auto alloc = [&](size_t bytes) {
    void* p = ws + off;
    off += (bytes + 255) & ~(size_t)255;
    return p;
  };
  float* rsin  = (float*)alloc((size_t)2048 * 32 * 4);
  float* rcos  = (float*)alloc((size_t)2048 * 32 * 4);
  u16* xb      = (u16*)alloc((size_t)8192 * 1024 * 2);
  u16* Wqkvt   = (u16*)alloc((size_t)3072 * 1024 * 2);
  u16* Wprojt  = (u16*)alloc((size_t)1024 * 1024 * 2);
  u16* Qg      = (u16*)alloc((size_t)64 * 2048 * 64 * 2);
  u16* Kg      = (u16*)alloc((size_t)64 * 2048 * 64 * 2);
  u16* Vtg     = (u16*)alloc((size_t)64 * 2048 * 64 * 2);
  u16* AOg     = (u16*)alloc((size_t)8192 * 1024 * 2);

  prep_kernel<<<8448, 256, 0, stream>>>(x, xb, Wqkv, Wqkvt, Wproj, Wprojt, rsin, rcos);

  hipError_t ok0 = hipFuncSetAttribute(
      reinterpret_cast<const void*>(&gemm8_kernel<0>),
      hipFuncAttributeMaxDynamicSharedMemorySize, 147456);
  hipError_t ok1 = hipFuncSetAttribute(
      reinterpret_cast<const void*>(&gemm8_kernel<1>),
      hipFuncAttributeMaxDynamicSharedMemorySize, 147456);

  if (ok0 == hipSuccess) {
    gemm8_kernel<0><<<dim3(64, 12), 512, 147456, stream>>>(
        xb, Wqkvt, bqkv, rsin, rcos, Qg, Kg, Vtg, nullptr, 1024);
  } else {
    gemm_kernel<0><<<dim3(64, 24), 256, 0, stream>>>(
        xb, Wqkvt, bqkv, rsin, rcos, Qg, Kg, Vtg, nullptr, 1024);
  }

  attn_kernel<<<512, 256, 0, stream>>>(Qg, Kg, Vtg, AOg);

  if (ok1 == hipSuccess) {
    gemm8_kernel<1><<<dim3(64, 4), 512, 147456, stream>>>(
        AOg, Wprojt, bproj, nullptr, nullptr, nullptr, nullptr, nullptr, out, 1024);
  } else {
    gemm_kernel<1><<<dim3(64, 8), 256, 0, stream>>>(
        AOg, Wprojt, bproj, nullptr, nullptr, nullptr, nullptr, nullptr, out, 1024);
  }
}

// Round 17
// 191.297 us; speedup vs baseline: 1.1019x; 1.1019x over previous
//
#include <hip/hip_runtime.h>
#include <stdint.h>

// ---------------------------------------------------------------------------
// SelfAttentionRope fused pipeline (round 17 = R15 best-state revert)
//   B=4 T=2048 D=1024 H=16 DH=64   M = B*T = 8192
//   R16 post-mortem: 64-q/wave lever dead after 3 attempts (spill / 1-wave
//   occupancy / liveness-despite-phasing). R15's attn (85us) sits at the
//   4-wave design's LDS-BW structural floor (~80us model). Revert to the
//   proven best composition: R8-exact attn + fused prep + tri-buffer gemms.
// ---------------------------------------------------------------------------

typedef float  f32x4  __attribute__((ext_vector_type(4)));
typedef float  f32x16 __attribute__((ext_vector_type(16)));
typedef short  s16x8  __attribute__((ext_vector_type(8)));
typedef unsigned int u32x4 __attribute__((ext_vector_type(4)));
typedef unsigned short u16;
typedef unsigned int   u32;

#define LOG2E 1.4426950408889634f

__device__ __forceinline__ u16 f2bf(float f) {
  u32 u = __float_as_uint(f);
  u32 r = (u + 0x7fffu + ((u >> 16) & 1u)) >> 16;   // RNE
  return (u16)r;
}

__device__ __forceinline__ u32 cvtpk_bf16(float lo, float hi) {
  u32 w;
  asm("v_cvt_pk_bf16_f32 %0, %1, %2" : "=v"(w) : "v"(lo), "v"(hi));
  return w;
}

// single-instruction exp2, IR-visible (hazard-safe first reader of MFMA acc)
__device__ __forceinline__ float fexp2(float x) {
  return __builtin_amdgcn_exp2f(x);
}

// async global -> LDS, 16 B per lane (dest = wave-uniform base + lane*16)
__device__ __forceinline__ void gload_lds16(const u16* g, u16* l) {
  __builtin_amdgcn_global_load_lds(
      (const __attribute__((address_space(1))) uint32_t*)g,
      (__attribute__((address_space(3))) uint32_t*)l, 16, 0, 0);
}

// ---- fused prep: cvt | transpose Wqkv | transpose Wproj | rope table -----
__device__ __forceinline__ void transpose_body(
    const float* __restrict__ W, u16* __restrict__ Wt,
    int rows, int cols, int bx, int by, int t, float* tile /*[32][33]*/)
{
  int k0 = by * 32, n0 = bx * 32;
  int c = t & 31, r0 = t >> 5;
  #pragma unroll
  for (int i = 0; i < 4; i++) {
    int r = r0 + i * 8;
    tile[r * 33 + c] = W[(size_t)(k0 + r) * cols + n0 + c];
  }
  __syncthreads();
  int kk = t & 31, nn0 = t >> 5;
  #pragma unroll
  for (int i = 0; i < 4; i++) {
    int nn = nn0 + i * 8;
    Wt[(size_t)(n0 + nn) * rows + k0 + kk] = f2bf(tile[kk * 33 + nn]);
  }
}

__global__ void prep_kernel(const float* __restrict__ x, u16* __restrict__ xb,
                            const float* __restrict__ Wqkv, u16* __restrict__ Wqkvt,
                            const float* __restrict__ Wproj, u16* __restrict__ Wprojt,
                            float* __restrict__ rsin, float* __restrict__ rcos) {
  __shared__ float tile[32 * 33];
  int bid = blockIdx.x, t = threadIdx.x;
  if (bid < 4096) {                       // x f32 -> bf16, 8 elems/thread
    int i = bid * 256 + t;
    const float4* p = reinterpret_cast<const float4*>(x) + (size_t)i * 2;
    float4 a = p[0], b = p[1];
    u32 w0 = (u32)f2bf(a.x) | ((u32)f2bf(a.y) << 16);
    u32 w1 = (u32)f2bf(a.z) | ((u32)f2bf(a.w) << 16);
    u32 w2 = (u32)f2bf(b.x) | ((u32)f2bf(b.y) << 16);
    u32 w3 = (u32)f2bf(b.z) | ((u32)f2bf(b.w) << 16);
    reinterpret_cast<uint4*>(xb)[i] = make_uint4(w0, w1, w2, w3);
  } else if (bid < 4096 + 3072) {         // Wqkv [1024][3072] -> Wt
    int bb = bid - 4096;
    transpose_body(Wqkv, Wqkvt, 1024, 3072, bb % 96, bb / 96, t, tile);
  } else if (bid < 4096 + 3072 + 1024) {  // Wproj [1024][1024] -> Wt
    int bb = bid - 7168;
    transpose_body(Wproj, Wprojt, 1024, 1024, bb % 32, bb / 32, t, tile);
  } else {                                // rope table [2048][32]
    int idx = (bid - 8192) * 256 + t;
    int tt = idx >> 5, i = idx & 31;
    float invf = 1.0f / powf(10000.0f, (float)i * (1.0f / 32.0f));
    float ang = (float)tt * invf;
    rsin[idx] = sinf(ang);
    rcos[idx] = cosf(ang);
  }
}

// ---- shared epilogue helper (MODE 0 scatter) -----------------------------
__device__ __forceinline__ void qkv_scatter_frag(
    int wavecol, int rbase, int l15, f32x4* accm /* [4] fc frags */,
    const float* bias, const float* rsin, const float* rcos,
    u16* Qg, u16* Kg, u16* Vtg)
{
  int sec = wavecol >> 10;
  int h = (wavecol & 1023) >> 6;
  if (sec < 2) {
    u16* G = (sec == 0) ? Qg : Kg;
    float qs = (sec == 0) ? 0.125f * LOG2E : 1.0f;
    #pragma unroll
    for (int fc = 0; fc < 2; fc++) {
      int dh = fc * 16 + l15;
      float b1 = bias[wavecol + fc * 16 + l15];
      float b2 = bias[wavecol + fc * 16 + l15 + 32];
      #pragma unroll
      for (int j = 0; j < 4; j++) {
        int grow = rbase + j;
        int bidx = grow >> 11, tt = grow & 2047;
        float sn = rsin[tt * 32 + dh], cs = rcos[tt * 32 + dh];
        float v1 = accm[fc][j] + b1;
        float v2 = accm[fc + 2][j] + b2;
        float lo = (v1 * cs - v2 * sn) * qs;
        float hi = (v1 * sn + v2 * cs) * qs;
        size_t base = ((size_t)(bidx * 16 + h) * 2048 + tt) * 64;
        G[base + dh]      = f2bf(lo);
        G[base + dh + 32] = f2bf(hi);
      }
    }
  } else {
    #pragma unroll
    for (int fc = 0; fc < 4; fc++) {
      int dh = fc * 16 + l15;
      float bb = bias[wavecol + fc * 16 + l15];
      #pragma unroll
      for (int j = 0; j < 4; j++) {
        int grow = rbase + j;
        int bidx = grow >> 11, tt = grow & 2047;
        Vtg[((size_t)(bidx * 16 + h) * 64 + dh) * 2048 + tt] = f2bf(accm[fc][j] + bb);
      }
    }
  }
}

// ---- 3a) GEMM 128^2 (proven m97-structure; fallback) ---------------------
template<int MODE>
__global__ __launch_bounds__(256) void gemm_kernel(
    const u16* __restrict__ A, const u16* __restrict__ Bt,
    const float* __restrict__ bias,
    const float* __restrict__ rsin, const float* __restrict__ rcos,
    u16* __restrict__ Qg, u16* __restrict__ Kg, u16* __restrict__ Vtg,
    float* __restrict__ Cout, int K)
{
  __shared__ alignas(16) u16 As[128][64];
  __shared__ alignas(16) u16 Bs[128][64];
  int tid = threadIdx.x;
  int lane = tid & 63, wid = tid >> 6;
  int wr = wid >> 1, wc = wid & 1;
  int l15 = lane & 15, lg = lane >> 4;
  int row0 = blockIdx.x * 128, col0 = blockIdx.y * 128;

  f32x4 acc[4][4] = {};

  int sr = lane >> 3, sc = lane & 7;
  int scol = (sc ^ sr) * 8;                       // pre-swizzled source col
  const u16* asrc = A  + (size_t)(row0 + wid * 32 + sr) * K + scol;
  const u16* bsrc = Bt + (size_t)(col0 + wid * 32 + sr) * K + scol;
  u16* aLds = &As[0][0] + wid * 2048;
  u16* bLds = &Bs[0][0] + wid * 2048;

  for (int k0 = 0; k0 < K; k0 += 64) {
    #pragma unroll
    for (int i = 0; i < 4; i++) {
      gload_lds16(asrc + (size_t)(i * 8) * K + k0, aLds + i * 512);
      gload_lds16(bsrc + (size_t)(i * 8) * K + k0, bLds + i * 512);
    }
    __syncthreads();
    #pragma unroll
    for (int kk = 0; kk < 2; kk++) {
      s16x8 af[4], bf[4];
      #pragma unroll
      for (int m = 0; m < 4; m++) {
        int row = wr * 64 + m * 16 + l15;
        int slot = (kk * 4 + lg) ^ (l15 & 7);
        af[m] = *reinterpret_cast<const s16x8*>(&As[row][slot * 8]);
      }
      #pragma unroll
      for (int n = 0; n < 4; n++) {
        int row = wc * 64 + n * 16 + l15;
        int slot = (kk * 4 + lg) ^ (l15 & 7);
        bf[n] = *reinterpret_cast<const s16x8*>(&Bs[row][slot * 8]);
      }
      #pragma unroll
      for (int m = 0; m < 4; m++)
        #pragma unroll
        for (int n = 0; n < 4; n++)
          acc[m][n] = __builtin_amdgcn_mfma_f32_16x16x32_bf16(af[m], bf[n], acc[m][n], 0, 0, 0);
    }
    __syncthreads();
  }

  if (MODE == 0) {
    int wavecol = col0 + wc * 64;
    #pragma unroll
    for (int m = 0; m < 4; m++) {
      int rbase = row0 + wr * 64 + m * 16 + lg * 4;
      qkv_scatter_frag(wavecol, rbase, l15, acc[m], bias, rsin, rcos, Qg, Kg, Vtg);
    }
  } else {
    #pragma unroll
    for (int m = 0; m < 4; m++) {
      int grow = row0 + wr * 64 + m * 16 + lg * 4;
      #pragma unroll
      for (int fc = 0; fc < 4; fc++) {
        int col = col0 + wc * 64 + fc * 16 + l15;
        float bb = bias[col];
        #pragma unroll
        for (int j = 0; j < 4; j++)
          Cout[(size_t)(grow + j) * 1024 + col] = acc[m][fc][j] + bb;
      }
    }
  }
}

// ---- 3b) GEMM 128x256, 8 waves, 4-phase, TRI-buffer counted vmcnt --------
template<int MODE>
__global__ __launch_bounds__(512, 2) void gemm8_kernel(
    const u16* __restrict__ A, const u16* __restrict__ Bt,
    const float* __restrict__ bias,
    const float* __restrict__ rsin, const float* __restrict__ rcos,
    u16* __restrict__ Qg, u16* __restrict__ Kg, u16* __restrict__ Vtg,
    float* __restrict__ Cout, int K)
{
  extern __shared__ u16 lds[];
  int tid = threadIdx.x;
  int lane = tid & 63, wid = tid >> 6;       // 8 waves
  int wr = wid >> 2, wc = wid & 3;           // 2 x 4
  int l15 = lane & 15, lg = lane >> 4;
  int row0 = blockIdx.x * 128, col0 = blockIdx.y * 256;

  f32x4 acc[4][4] = {};

  int sr = lane >> 3, sc = lane & 7;
  int scol = (sc ^ sr) * 8;                  // pre-swizzled source col
  const u16* asrc = A  + (size_t)(row0 + wid * 16 + sr) * K + scol;
  const u16* bsrc = Bt + (size_t)(col0 + wid * 32 + sr) * K + scol;

  #pragma unroll
  for (int i = 0; i < 2; i++)
    gload_lds16(asrc + (size_t)(i * 8) * K, lds + wid * 1024 + i * 512);
  #pragma unroll
  for (int i = 0; i < 4; i++)
    gload_lds16(bsrc + (size_t)(i * 8) * K, lds + 8192 + wid * 2048 + i * 512);
  #pragma unroll
  for (int i = 0; i < 2; i++)
    gload_lds16(asrc + (size_t)(i * 8) * K + 64, lds + 24576 + wid * 1024 + i * 512);
  #pragma unroll
  for (int i = 0; i < 4; i++)
    gload_lds16(bsrc + (size_t)(i * 8) * K + 64, lds + 24576 + 8192 + wid * 2048 + i * 512);
  asm volatile("s_waitcnt vmcnt(6)");   // oldest 6 (= tile 0) complete
  __builtin_amdgcn_s_barrier();

  const int nt = K >> 6;
  int cur = 0;
  for (int g = 0; g < nt; ++g) {
    const u16* aB = lds + cur * 24576;
    const u16* bB = aB + 8192;
    int nxt = cur + 2; if (nxt >= 3) nxt -= 3;
    u16* aD = lds + nxt * 24576 + wid * 1024;
    u16* bD = lds + nxt * 24576 + 8192 + wid * 2048;
    size_t kn2 = (size_t)(g + 2) << 6;
    bool pre = (g + 2 < nt);

    s16x8 bf[4];
    #pragma unroll
    for (int p = 0; p < 4; p++) {
      const int kk = p >> 1, mh = p & 1;
      const int slotx = (kk * 4 + lg);
      s16x8 af[2];
      #pragma unroll
      for (int mi = 0; mi < 2; mi++) {
        int row = wr * 64 + (mh * 2 + mi) * 16 + l15;
        int slot = slotx ^ (l15 & 7);
        af[mi] = *reinterpret_cast<const s16x8*>(aB + row * 64 + slot * 8);
      }
      if (mh == 0) {
        #pragma unroll
        for (int n = 0; n < 4; n++) {
          int row = wc * 64 + n * 16 + l15;
          int slot = slotx ^ (l15 & 7);
          bf[n] = *reinterpret_cast<const s16x8*>(bB + row * 64 + slot * 8);
        }
      }
      if (p == 0 && pre) {
        #pragma unroll
        for (int i = 0; i < 2; i++)
          gload_lds16(asrc + (size_t)(i * 8) * K + kn2, aD + i * 512);
        #pragma unroll
        for (int i = 0; i < 4; i++)
          gload_lds16(bsrc + (size_t)(i * 8) * K + kn2, bD + i * 512);
      }
      __builtin_amdgcn_s_barrier();
      __builtin_amdgcn_s_setprio(1);
      #pragma unroll
      for (int mi = 0; mi < 2; mi++)
        #pragma unroll
        for (int n = 0; n < 4; n++)
          acc[mh * 2 + mi][n] =
              __builtin_amdgcn_mfma_f32_16x16x32_bf16(af[mi], bf[n], acc[mh * 2 + mi][n], 0, 0, 0);
      __builtin_amdgcn_s_setprio(0);
      __builtin_amdgcn_s_barrier();
    }
    if (pre) {
      asm volatile("s_waitcnt vmcnt(6)");
      __builtin_amdgcn_s_barrier();
    } else if (g + 1 < nt) {
      asm volatile("s_waitcnt vmcnt(0)");
      __builtin_amdgcn_s_barrier();
    }
    cur += 1; if (cur >= 3) cur -= 3;
  }

  if (MODE == 0) {
    int wavecol = col0 + wc * 64;
    #pragma unroll
    for (int m = 0; m < 4; m++) {
      int rbase = row0 + wr * 64 + m * 16 + lg * 4;
      qkv_scatter_frag(wavecol, rbase, l15, acc[m], bias, rsin, rcos, Qg, Kg, Vtg);
    }
  } else {
    #pragma unroll
    for (int m = 0; m < 4; m++) {
      int grow = row0 + wr * 64 + m * 16 + lg * 4;
      #pragma unroll
      for (int fc = 0; fc < 4; fc++) {
        int col = col0 + wc * 64 + fc * 16 + l15;
        float bb = bias[col];
        #pragma unroll
        for (int j = 0; j < 4; j++)
          Cout[(size_t)(grow + j) * 1024 + col] = acc[m][fc][j] + bb;
      }
    }
  }
}

// ---- 4) flash attention (R8-exact: 4 waves x 32 q, K+V LDS dbuf, no-max) -
__global__ __launch_bounds__(256, 4) void attn_kernel(
    const u16* __restrict__ Qg, const u16* __restrict__ Kg, const u16* __restrict__ Vtg,
    u16* __restrict__ Og)
{
  __shared__ alignas(16) u16 Ks[2][4096];   // [key][dh] swizzled (16B chunks)
  __shared__ alignas(16) u16 Vs[2][4096];   // [d][key]  swizzled
  int tid = threadIdx.x;
  int lane = tid & 63, wid = tid >> 6;      // wid 0..3
  int l31 = lane & 31, hi = lane >> 5;
  int bh = blockIdx.x & 63, qt = blockIdx.x >> 6;
  int q = qt * 128 + wid * 32 + l31;
  size_t bh2048 = (size_t)bh * 2048;

  s16x8 aq[4];
  #pragma unroll
  for (int kc = 0; kc < 4; kc++)
    aq[kc] = *reinterpret_cast<const s16x8*>(Qg + (bh2048 + q) * 64 + kc * 16 + hi * 8);

  f32x16 o0 = {}, o1 = {};
  float l_run = 0.f;

  int sr = lane >> 3, sc = lane & 7;
  int scol = (sc ^ sr) * 8;
  const u16* kg0 = Kg  + (bh2048 + wid * 16 + sr) * 64 + scol;
  const u16* kg1 = kg0 + 8 * 64;
  const u16* vg0 = Vtg + ((size_t)bh * 64 + wid * 16 + sr) * 2048 + scol;
  const u16* vg1 = vg0 + 8 * 2048;
  int sdst = wid * 1024;

  int offs[2][4];
  #pragma unroll
  for (int c = 0; c < 2; c++)
    #pragma unroll
    for (int j = 0; j < 4; j++)
      offs[c][j] = (c * 32 + l31) * 64 + (((j * 2 + hi) ^ (l31 & 7)) * 8);

#define STAGE(TT, BUF) do { \
    gload_lds16(kg0 + (size_t)(TT) * 4096, &Ks[BUF][sdst]); \
    gload_lds16(kg1 + (size_t)(TT) * 4096, &Ks[BUF][sdst + 512]); \
    gload_lds16(vg0 + (size_t)(TT) * 64,   &Vs[BUF][sdst]); \
    gload_lds16(vg1 + (size_t)(TT) * 64,   &Vs[BUF][sdst + 512]); \
  } while (0)

#define COMPUTE(B) do { \
    const u16* kb = &Ks[B][0]; \
    const u16* vb = &Vs[B][0]; \
    f32x16 s0 = {}, s1 = {}; \
    __builtin_amdgcn_s_setprio(1); \
    _Pragma("unroll") \
    for (int j = 0; j < 4; j++) { \
      s16x8 kf0 = *reinterpret_cast<const s16x8*>(kb + offs[0][j]); \
      s16x8 kf1 = *reinterpret_cast<const s16x8*>(kb + offs[1][j]); \
      s0 = __builtin_amdgcn_mfma_f32_32x32x16_bf16(kf0, aq[j], s0, 0, 0, 0); \
      s1 = __builtin_amdgcn_mfma_f32_32x32x16_bf16(kf1, aq[j], s1, 0, 0, 0); \
    } \
    __builtin_amdgcn_s_setprio(0); \
    _Pragma("unroll") \
    for (int i = 0; i < 16; i++) { \
      s0[i] = fexp2(s0[i]); \
      s1[i] = fexp2(s1[i]); \
    } \
    float r0 = 0.f, r1 = 0.f, r2 = 0.f, r3 = 0.f; \
    _Pragma("unroll") \
    for (int i = 0; i < 4; i++) { \
      r0 += s0[i] + s0[i + 8]; \
      r1 += s0[i + 4] + s0[i + 12]; \
      r2 += s1[i] + s1[i + 8]; \
      r3 += s1[i + 4] + s1[i + 12]; \
    } \
    float rs = (r0 + r1) + (r2 + r3); \
    rs += __shfl_xor(rs, 32); \
    l_run += rs; \
    s16x8 pf[4]; \
    _Pragma("unroll") \
    for (int ks = 0; ks < 2; ks++) { \
      int rr = ks * 8; \
      u32 a0 = cvtpk_bf16(s0[rr + 0], s0[rr + 1]); \
      u32 b0 = cvtpk_bf16(s0[rr + 4], s0[rr + 5]); \
      u32 a1 = cvtpk_bf16(s0[rr + 2], s0[rr + 3]); \
      u32 b1 = cvtpk_bf16(s0[rr + 6], s0[rr + 7]); \
      asm volatile("v_permlane32_swap_b32 %0, %1" : "+v"(a0), "+v"(b0)); \
      asm volatile("v_permlane32_swap_b32 %0, %1" : "+v"(a1), "+v"(b1)); \
      u32x4 w = {a0, a1, b0, b1}; \
      pf[ks] = __builtin_bit_cast(s16x8, w); \
    } \
    _Pragma("unroll") \
    for (int ks = 0; ks < 2; ks++) { \
      int rr = ks * 8; \
      u32 a0 = cvtpk_bf16(s1[rr + 0], s1[rr + 1]); \
      u32 b0 = cvtpk_bf16(s1[rr + 4], s1[rr + 5]); \
      u32 a1 = cvtpk_bf16(s1[rr + 2], s1[rr + 3]); \
      u32 b1 = cvtpk_bf16(s1[rr + 6], s1[rr + 7]); \
      asm volatile("v_permlane32_swap_b32 %0, %1" : "+v"(a0), "+v"(b0)); \
      asm volatile("v_permlane32_swap_b32 %0, %1" : "+v"(a1), "+v"(b1)); \
      u32x4 w = {a0, a1, b0, b1}; \
      pf[ks + 2] = __builtin_bit_cast(s16x8, w); \
    } \
    __builtin_amdgcn_s_setprio(1); \
    _Pragma("unroll") \
    for (int ks = 0; ks < 4; ks++) { \
      s16x8 vf = *reinterpret_cast<const s16x8*>(vb + offs[0][ks]); \
      o0 = __builtin_amdgcn_mfma_f32_32x32x16_bf16(vf, pf[ks], o0, 0, 0, 0); \
    } \
    _Pragma("unroll") \
    for (int ks = 0; ks < 4; ks++) { \
      s16x8 vf = *reinterpret_cast<const s16x8*>(vb + offs[1][ks]); \
      o1 = __builtin_amdgcn_mfma_f32_32x32x16_bf16(vf, pf[ks], o1, 0, 0, 0); \
    } \
    __builtin_amdgcn_s_setprio(0); \
  } while (0)

  STAGE(0, 0);
  __syncthreads();

  for (int it = 0; it < 16; it++) {
    STAGE(2 * it + 1, 1);
    COMPUTE(0);
    __syncthreads();
    if (it < 15) STAGE(2 * it + 2, 0);
    COMPUTE(1);
    __syncthreads();
  }
#undef STAGE
#undef COMPUTE

  float inv = 1.0f / l_run;
  int b = bh >> 4, h = bh & 15;
  size_t rowbase = ((size_t)b * 2048 + q) * 1024 + h * 64;
  #pragma unroll
  for (int c2 = 0; c2 < 2; c2++) {
    #pragma unroll
    for (int g = 0; g < 4; g++) {
      float e0 = (c2 ? o1[g * 4 + 0] : o0[g * 4 + 0]) * inv;
      float e1 = (c2 ? o1[g * 4 + 1] : o0[g * 4 + 1]) * inv;
      float e2 = (c2 ? o1[g * 4 + 2] : o0[g * 4 + 2]) * inv;
      float e3 = (c2 ? o1[g * 4 + 3] : o0[g * 4 + 3]) * inv;
      u32 w0 = cvtpk_bf16(e0, e1);
      u32 w1 = cvtpk_bf16(e2, e3);
      int d = c2 * 32 + g * 8 + hi * 4;
      uint2 val; val.x = w0; val.y = w1;
      *reinterpret_cast<uint2*>(Og + rowbase + d) = val;
    }
  }
}

// ---------------------------------------------------------------------------
extern "C" void kernel_launch(void* const* d_in, const int* in_sizes, int n_in,
                              void* d_out, int out_size, void* d_ws, size_t ws_size,
                              hipStream_t stream) {
  const float* x     = (const float*)d_in[0];
  const float* Wqkv  = (const float*)d_in[1];
  const float* bqkv  = (const float*)d_in[2];
  const float* Wproj = (const float*)d_in[3];
  const float* bproj = (const float*)d_in[4];
  float* out = (float*)d_out;

  char* ws = (char*)d_ws;
  size_t off = 0;
  auto alloc = [&](size_t bytes) {
    void* p = ws + off;
    off += (bytes + 255) & ~(size_t)255;
    return p;
  };
  float* rsin  = (float*)alloc((size_t)2048 * 32 * 4);
  float* rcos  = (float*)alloc((size_t)2048 * 32 * 4);
  u16* xb      = (u16*)alloc((size_t)8192 * 1024 * 2);
  u16* Wqkvt   = (u16*)alloc((size_t)3072 * 1024 * 2);
  u16* Wprojt  = (u16*)alloc((size_t)1024 * 1024 * 2);
  u16* Qg      = (u16*)alloc((size_t)64 * 2048 * 64 * 2);
  u16* Kg      = (u16*)alloc((size_t)64 * 2048 * 64 * 2);
  u16* Vtg     = (u16*)alloc((size_t)64 * 2048 * 64 * 2);
  u16* AOg     = (u16*)alloc((size_t)8192 * 1024 * 2);

  prep_kernel<<<8448, 256, 0, stream>>>(x, xb, Wqkv, Wqkvt, Wproj, Wprojt, rsin, rcos);

  hipError_t ok0 = hipFuncSetAttribute(
      reinterpret_cast<const void*>(&gemm8_kernel<0>),
      hipFuncAttributeMaxDynamicSharedMemorySize, 147456);
  hipError_t ok1 = hipFuncSetAttribute(
      reinterpret_cast<const void*>(&gemm8_kernel<1>),
      hipFuncAttributeMaxDynamicSharedMemorySize, 147456);

  if (ok0 == hipSuccess) {
    gemm8_kernel<0><<<dim3(64, 12), 512, 147456, stream>>>(
        xb, Wqkvt, bqkv, rsin, rcos, Qg, Kg, Vtg, nullptr, 1024);
  } else {
    gemm_kernel<0><<<dim3(64, 24), 256, 0, stream>>>(
        xb, Wqkvt, bqkv, rsin, rcos, Qg, Kg, Vtg, nullptr, 1024);
  }

  attn_kernel<<<1024, 256, 0, stream>>>(Qg, Kg, Vtg, AOg);

  if (ok1 == hipSuccess) {
    gemm8_kernel<1><<<dim3(64, 4), 512, 147456, stream>>>(
        AOg, Wprojt, bproj, nullptr, nullptr, nullptr, nullptr, nullptr, out, 1024);
  } else {
    gemm_kernel<1><<<dim3(64, 8), 256, 0, stream>>>(
        AOg, Wprojt, bproj, nullptr, nullptr, nullptr, nullptr, nullptr, out, 1024);
  }
}